// Round 4
// baseline (303.657 us; speedup 1.0000x reference)
//
#include <hip/hip_runtime.h>
#include <math.h>

#define NN 100000
#define NP 100032   // 64 * 1563 (padded node count)
#define NE 2000000
#define FIN 32
#define H 32
#define NC 40

#define NBK 196      // coarse buckets: dst>>9 (512 nodes each)
#define BSH 9
#define CAP 10880    // per-bucket capacity: mean 10240 + ~6.3 sigma
#define EPT 16
#define EPB (256 * EPT)  // 4096 edges per block

typedef _Float16 half_t;
typedef __attribute__((ext_vector_type(8))) _Float16 half8;
typedef __attribute__((ext_vector_type(4))) _Float16 half4;
typedef __attribute__((ext_vector_type(4))) float f32x4;
typedef long long ll2 __attribute__((ext_vector_type(2)));

__device__ __forceinline__ float sigm_(float x) {
    return 1.0f / (1.0f + __expf(-x));
}
__device__ __forceinline__ float tanh_(float x) {
    x = fminf(fmaxf(x, -20.0f), 20.0f);
    float e = __expf(2.0f * x);
    return (e - 1.0f) / (e + 1.0f);
}

// ---------- phase A: coarse-bucket scatter with LDS staging ----------
__global__ __launch_bounds__(256) void kA_bucket(const int* __restrict__ ei,
                                                 const float* __restrict__ ew,
                                                 int* __restrict__ gcur,
                                                 long long* __restrict__ rec) {
    __shared__ long long recs[EPB];   // 32 KB bucket-sorted records
    __shared__ int gdst[EPB];         // 16 KB absolute global slot per record
    __shared__ int cnt[NBK], base[NBK], sofs[NBK];
    __shared__ int ssc[256];
    int tid = threadIdx.x;
    for (int i = tid; i < NBK; i += 256) cnt[i] = 0;
    __syncthreads();
    int e0 = blockIdx.x * EPB;
    int dcache[EPT];
#pragma unroll
    for (int i = 0; i < EPT; ++i) {
        int e = e0 + i * 256 + tid;
        dcache[i] = (e < NE) ? ei[NE + e] : -1;
        if (e < NE) atomicAdd(&cnt[dcache[i] >> BSH], 1);
    }
    __syncthreads();
    int cv = (tid < NBK) ? cnt[tid] : 0;
    ssc[tid] = cv;
    __syncthreads();
    for (int off = 1; off < 256; off <<= 1) {
        int v = (tid >= off) ? ssc[tid - off] : 0;
        __syncthreads();
        ssc[tid] += v;
        __syncthreads();
    }
    if (tid < NBK) {
        sofs[tid] = ssc[tid] - cv;
        base[tid] = atomicAdd(&gcur[tid], cv);  // one global atomic per (block,bucket)
        cnt[tid] = 0;                           // reuse as rank cursor
    }
    __syncthreads();
#pragma unroll
    for (int i = 0; i < EPT; ++i) {
        int e = e0 + i * 256 + tid;
        if (e < NE) {
            int d = dcache[i], s = ei[e];
            int b = d >> BSH;
            int r = atomicAdd(&cnt[b], 1);
            int slot = sofs[b] + r;
            int pos = base[b] + r;
            int lo = s | ((d & 511) << 17);
            recs[slot] = (long long)(unsigned)lo |
                         ((long long)__float_as_int(ew[e]) << 32);
            gdst[slot] = (pos < CAP) ? (b * CAP + pos) : -1;  // overflow guard
        }
    }
    __syncthreads();
    int nrec = min(EPB, NE - e0);
    for (int i = tid; i < nrec; i += 256) {
        int gd = gdst[i];
        if (gd >= 0) rec[gd] = recs[i];
    }
}

// ---------- phase B: per-bucket counting sort by (dst_local, src_slice) ----------
// Round-17: dst-MAJOR slice-MINOR keys. Node's edges contiguous (single ofs/ocn,
// one head/tail, full-degree runs -> divergence 1.55x not 2x) but slice-ordered
// within the node: waves advance through edge positions ~synchronously, so the
// grid still gathers from ~2 adjacent ~2.1 MB slices at a time (XCD L2 resident;
// round-2 proved slice residency cuts FETCH 130->66 MB).
__global__ __launch_bounds__(256) void kB_sort(const int* __restrict__ gcur,
                                               const int2* __restrict__ rec,
                                               int2* __restrict__ evs,
                                               int* __restrict__ ofs,
                                               int* __restrict__ ocn) {
    __shared__ int hist[2048], lofs[2048], ssc[256];
    int tid = threadIdx.x, b = blockIdx.x;
    int nb0 = b << BSH;
    int nnodes = min(512, NN - nb0);
    int cntb = min(gcur[b], CAP);
    for (int i = tid; i < 2048; i += 256) hist[i] = 0;
    __syncthreads();
    const int2* rb = rec + (size_t)b * CAP;
    for (int i = tid; i < cntb; i += 256) {
        int rx = rb[i].x;
        int bin = (((rx >> 17) & 511) << 2) | ((rx & 0x1FFFF) >> 15);
        atomicAdd(&hist[bin], 1);
    }
    __syncthreads();
    // scan 2048 bins: 8 contiguous bins/thread, block scan of per-thread sums
    int base = tid * 8, ls = 0, lh[8];
#pragma unroll
    for (int j = 0; j < 8; ++j) {
        lh[j] = hist[base + j];
        ls += lh[j];
    }
    ssc[tid] = ls;
    __syncthreads();
    for (int off = 1; off < 256; off <<= 1) {
        int v = (tid >= off) ? ssc[tid - off] : 0;
        __syncthreads();
        ssc[tid] += v;
        __syncthreads();
    }
    int ex = ssc[tid] - ls;
#pragma unroll
    for (int j = 0; j < 8; ++j) {
        lofs[base + j] = ex;
        ex += lh[j];
    }
    __syncthreads();
    // per-node CSR meta: start = first slice bin, count = sum of 4 slice bins
    for (int l = tid; l < nnodes; l += 256) {
        int c = hist[4 * l] + hist[4 * l + 1] + hist[4 * l + 2] + hist[4 * l + 3];
        ofs[nb0 + l] = b * CAP + lofs[4 * l];
        ocn[nb0 + l] = c;
    }
    __syncthreads();
    for (int i = tid; i < 2048; i += 256) hist[i] = 0;
    __syncthreads();
    int2* eb = evs + (size_t)b * CAP;
    for (int i = tid; i < cntb; i += 256) {
        int2 r = rb[i];
        int bin = (((r.x >> 17) & 511) << 2) | ((r.x & 0x1FFFF) >> 15);
        int rk = atomicAdd(&hist[bin], 1);
        eb[lofs[bin] + rk] = make_int2(r.x & 0x1FFFF, r.y);
    }
}

// ---------- stage 1 of layer-2 weight fold (also zeroes gcur, replaces memset) ----------
__global__ __launch_bounds__(256) void k_wpre(const float* __restrict__ W2m,
                                              const float* __restrict__ wih2,
                                              float* __restrict__ M2,
                                              int* __restrict__ gcur) {
    int i = blockIdx.x * 256 + threadIdx.x;
    if (i < NBK) gcur[i] = 0;
    if (i >= NC * 3 * NC) return;
    int u = i / (3 * NC), col = i % (3 * NC);
    float acc = 0.f;
#pragma unroll
    for (int t = 0; t < NC; ++t) acc += W2m[u * NC + t] * wih2[col * NC + t];
    M2[i] = acc;
}

// ---------- build MFMA B-fragment-linear fp16 weight tables ----------
__global__ __launch_bounds__(256) void k_wc(const float* __restrict__ W1m,
                                            const float* __restrict__ wih1,
                                            const float* __restrict__ W2p,
                                            const float* __restrict__ M2,
                                            const float* __restrict__ whh1,
                                            const float* __restrict__ whh2,
                                            half_t* __restrict__ W1sw,
                                            half_t* __restrict__ W2sw) {
    int i = blockIdx.x * 256 + threadIdx.x;
    if (i < 8192) {
        int j = i & 7, lane = (i >> 3) & 63, ct = (i >> 9) & 7, s = i >> 12;
        int k = s * 32 + (lane >> 4) * 8 + j;
        int col = ct * 16 + (lane & 15);
        int g = col >> 5, jj = col & 31;
        float v = 0.f;
        if (g <= 2) {
            if (k < 32) {  // input side (agg): fold W1m @ wih1^T
                float acc = 0.f;
#pragma unroll
                for (int t = 0; t < H; ++t) acc += W1m[k * H + t] * wih1[(g * H + jj) * H + t];
                v = acc;
            } else if (g < 2) {  // r,z hidden side
                v = whh1[(g * H + jj) * H + (k - 32)];
            }                     // g==2 (i_n), k>=32 -> 0
        } else {                  // g==3 (h_n): hidden side only
            if (k >= 32) v = whh1[(2 * H + jj) * H + (k - 32)];
        }
        W1sw[i] = (half_t)v;
    } else if (i < 8192 + 18432) {
        int i2 = i - 8192;
        int j = i2 & 7, lane = (i2 >> 3) & 63;
        int tt = i2 >> 9;  // 0..35
        int ct = tt % 12, s = tt / 12;
        int k = s * 32 + (lane >> 4) * 8 + j;  // 0..95
        int col = ct * 16 + (lane & 15);       // 0..191
        int g = col / 48, jj = col % 48;
        float v = 0.f;
        if (jj < NC) {
            if (g <= 2) {
                if (k < 32) {  // input side (aggX): W2p @ M2 (stage-1 precomputed)
                    float acc = 0.f;
#pragma unroll
                    for (int u = 0; u < NC; ++u)
                        acc += W2p[k * NC + u] * M2[u * 3 * NC + g * NC + jj];
                    v = acc;
                } else if (k < 72 && g < 2) {  // r,z hidden side
                    v = whh2[(g * NC + jj) * NC + (k - 32)];
                }
            } else {  // g==3 (h_n)
                if (k >= 32 && k < 72) v = whh2[(2 * NC + jj) * NC + (k - 32)];
            }
        }
        W2sw[i2] = (half_t)v;
    }
}

// ---------- K1: h1 = x @ W1p -> fp16 into Xc1 cols 32..63 AND dense Hd [NN][32] ----------
__global__ __launch_bounds__(256) void k1_proj(const float* __restrict__ x,
                                               const float* __restrict__ Wp,
                                               half_t* __restrict__ Xc1,
                                               half_t* __restrict__ Hd) {
    __shared__ float sWp[FIN * H];
    __shared__ float sx[8][FIN];
    int tid = threadIdx.x;
    for (int i = tid; i < FIN * H; i += 256) sWp[i] = Wp[i];
    int nb = blockIdx.x * 8;
    int nl = tid >> 5, j = tid & 31;
    int n = nb + nl;
    if (n < NN) sx[nl][j] = x[(size_t)n * FIN + j];
    __syncthreads();
    float acc = 0.f;
#pragma unroll
    for (int k = 0; k < FIN; ++k) acc += sx[nl][k] * sWp[k * H + j];
    if (n < NN) {
        half_t hv = (half_t)acc;
        Xc1[(size_t)n * 64 + 32 + j] = hv;
        Hd[(size_t)n * 32 + j] = hv;
    }
}

// ---------- K4: h2 = hrelu @ W2p -> fp16 into Xc2 cols 32..71 (stride 96); zero pad 72..95 ----------
__global__ __launch_bounds__(320) void k4_proj2(const half_t* __restrict__ Hh,
                                                const float* __restrict__ Wp,
                                                half_t* __restrict__ Xc2) {
    __shared__ float sWp[FIN * NC];
    __shared__ float shn[8][FIN];
    int tid = threadIdx.x;
    for (int i = tid; i < FIN * NC; i += 320) sWp[i] = Wp[i];
    int nb = blockIdx.x * 8;
    if (tid < 256) {
        int r = tid >> 5, c = tid & 31;
        shn[r][c] = (float)Hh[(size_t)(nb + r) * 32 + c];
    }
    // zero K-pad cols 72..95 (stale scratch can be fp16-NaN; MFMA 0*NaN = NaN)
    if (tid < 192) {
        int r = tid / 24, c = tid % 24;
        Xc2[(size_t)(nb + r) * 96 + 72 + c] = (half_t)0.f;
    }
    __syncthreads();
    int nl = tid / NC, j = tid % NC;
    int n = nb + nl;
    float acc = 0.f;
#pragma unroll
    for (int k = 0; k < FIN; ++k) acc += shn[nl][k] * sWp[k * NC + j];
    if (n < NN) Xc2[(size_t)n * 96 + 32 + j] = (half_t)acc;
}

// ---------- aggregation: contiguous per-node runs, slice-ordered within node ----------
// 4 lanes/node, 16B half8 gathers, 8-edge main loop (8 gathers + 4 record-pair
// loads in flight). evs loads nontemporal (single-use 16 MB stream).
template <int DSTR>
__global__ __launch_bounds__(256) void k_aggh(const int* __restrict__ ofs,
                                              const int* __restrict__ ocn,
                                              const int2* __restrict__ evs,
                                              const half_t* __restrict__ src,
                                              half_t* __restrict__ dst) {
    int idx = blockIdx.x * 256 + threadIdx.x;
    int n = idx >> 2, q = idx & 3;
    if (n >= NN) return;
    const half8* s8 = (const half8*)src + q;       // 16B column chunk; row stride 4 half8
    const long long* ev8 = (const long long*)evs;  // packed (src, w)
    int e = ofs[n];
    int e1 = e + ocn[n];
    float acc[8] = {0.f, 0.f, 0.f, 0.f, 0.f, 0.f, 0.f, 0.f};
    if ((e & 1) && e < e1) {  // head: align to 16B for pair loads
        long long r = __builtin_nontemporal_load(ev8 + e);
        float w = __int_as_float((int)(r >> 32));
        half8 hv = s8[(size_t)(r & 0x1FFFF) * 4];
#pragma unroll
        for (int t = 0; t < 8; ++t) acc[t] += w * (float)hv[t];
        ++e;
    }
    for (; e + 8 <= e1; e += 8) {
        ll2 p0 = __builtin_nontemporal_load((const ll2*)(ev8 + e));
        ll2 p1 = __builtin_nontemporal_load((const ll2*)(ev8 + e + 2));
        ll2 p2 = __builtin_nontemporal_load((const ll2*)(ev8 + e + 4));
        ll2 p3 = __builtin_nontemporal_load((const ll2*)(ev8 + e + 6));
        half8 h0 = s8[(size_t)(p0[0] & 0x1FFFF) * 4];
        half8 h1 = s8[(size_t)(p0[1] & 0x1FFFF) * 4];
        half8 h2 = s8[(size_t)(p1[0] & 0x1FFFF) * 4];
        half8 h3 = s8[(size_t)(p1[1] & 0x1FFFF) * 4];
        half8 h4 = s8[(size_t)(p2[0] & 0x1FFFF) * 4];
        half8 h5 = s8[(size_t)(p2[1] & 0x1FFFF) * 4];
        half8 h6 = s8[(size_t)(p3[0] & 0x1FFFF) * 4];
        half8 h7 = s8[(size_t)(p3[1] & 0x1FFFF) * 4];
        float w0 = __int_as_float((int)(p0[0] >> 32));
        float w1 = __int_as_float((int)(p0[1] >> 32));
        float w2 = __int_as_float((int)(p1[0] >> 32));
        float w3 = __int_as_float((int)(p1[1] >> 32));
        float w4 = __int_as_float((int)(p2[0] >> 32));
        float w5 = __int_as_float((int)(p2[1] >> 32));
        float w6 = __int_as_float((int)(p3[0] >> 32));
        float w7 = __int_as_float((int)(p3[1] >> 32));
#pragma unroll
        for (int t = 0; t < 8; ++t) {
            acc[t] += w0 * (float)h0[t];
            acc[t] += w1 * (float)h1[t];
            acc[t] += w2 * (float)h2[t];
            acc[t] += w3 * (float)h3[t];
            acc[t] += w4 * (float)h4[t];
            acc[t] += w5 * (float)h5[t];
            acc[t] += w6 * (float)h6[t];
            acc[t] += w7 * (float)h7[t];
        }
    }
    if (e + 4 <= e1) {
        ll2 p0 = __builtin_nontemporal_load((const ll2*)(ev8 + e));
        ll2 p1 = __builtin_nontemporal_load((const ll2*)(ev8 + e + 2));
        half8 h0 = s8[(size_t)(p0[0] & 0x1FFFF) * 4];
        half8 h1 = s8[(size_t)(p0[1] & 0x1FFFF) * 4];
        half8 h2 = s8[(size_t)(p1[0] & 0x1FFFF) * 4];
        half8 h3 = s8[(size_t)(p1[1] & 0x1FFFF) * 4];
        float w0 = __int_as_float((int)(p0[0] >> 32));
        float w1 = __int_as_float((int)(p0[1] >> 32));
        float w2 = __int_as_float((int)(p1[0] >> 32));
        float w3 = __int_as_float((int)(p1[1] >> 32));
#pragma unroll
        for (int t = 0; t < 8; ++t) {
            acc[t] += w0 * (float)h0[t];
            acc[t] += w1 * (float)h1[t];
            acc[t] += w2 * (float)h2[t];
            acc[t] += w3 * (float)h3[t];
        }
        e += 4;
    }
    if (e + 2 <= e1) {
        ll2 p0 = __builtin_nontemporal_load((const ll2*)(ev8 + e));
        half8 h0 = s8[(size_t)(p0[0] & 0x1FFFF) * 4];
        half8 h1 = s8[(size_t)(p0[1] & 0x1FFFF) * 4];
        float w0 = __int_as_float((int)(p0[0] >> 32));
        float w1 = __int_as_float((int)(p0[1] >> 32));
#pragma unroll
        for (int t = 0; t < 8; ++t) {
            acc[t] += w0 * (float)h0[t];
            acc[t] += w1 * (float)h1[t];
        }
        e += 2;
    }
    if (e < e1) {  // tail single
        long long r = __builtin_nontemporal_load(ev8 + e);
        float w = __int_as_float((int)(r >> 32));
        half8 hv = s8[(size_t)(r & 0x1FFFF) * 4];
#pragma unroll
        for (int t = 0; t < 8; ++t) acc[t] += w * (float)hv[t];
    }
    half8 o;
#pragma unroll
    for (int t = 0; t < 8; ++t) o[t] = (half_t)acc[t];
    *(half8*)(dst + (size_t)n * DSTR + q * 8) = o;
}

// ---------- K3: GRU layer1 + relu via MFMA. 4 waves x 16 nodes, no LDS ----------
__global__ __launch_bounds__(256) void k3m(const half_t* __restrict__ Xc1,
                                           const half8* __restrict__ W1sw,
                                           const float* __restrict__ bih,
                                           const float* __restrict__ bhh,
                                           half_t* __restrict__ Hh) {
    int tid = threadIdx.x;
    int wave = tid >> 6, lane = tid & 63;
    int m16 = lane & 15, q = lane >> 4;
    int nb = blockIdx.x * 64 + wave * 16;
    const half8* xr = (const half8*)(Xc1 + (size_t)(nb + m16) * 64);
    half8 a0 = xr[q];      // k = q*8..q*8+7
    half8 a1 = xr[4 + q];  // k = 32+q*8..
    f32x4 acc[8];
#pragma unroll
    for (int ct = 0; ct < 8; ++ct) acc[ct] = (f32x4){0.f, 0.f, 0.f, 0.f};
#pragma unroll
    for (int ct = 0; ct < 8; ++ct) {
        acc[ct] = __builtin_amdgcn_mfma_f32_16x16x32_f16(a0, W1sw[ct * 64 + lane], acc[ct], 0, 0, 0);
        acc[ct] = __builtin_amdgcn_mfma_f32_16x16x32_f16(a1, W1sw[(8 + ct) * 64 + lane], acc[ct], 0, 0, 0);
    }
#pragma unroll
    for (int ct = 0; ct < 2; ++ct) {
        int j = ct * 16 + m16;
        float br = bih[j] + bhh[j];
        float bz = bih[H + j] + bhh[H + j];
        float bi = bih[2 * H + j], bh = bhh[2 * H + j];
#pragma unroll
        for (int m = 0; m < 4; ++m) {
            int node = nb + q * 4 + m;  // C/D: row = quad*4 + reg, col = lane&15
            float r = sigm_(acc[ct][m] + br);
            float z = sigm_(acc[2 + ct][m] + bz);
            float ng = tanh_(acc[4 + ct][m] + bi + r * (acc[6 + ct][m] + bh));
            float hj = (float)Xc1[(size_t)node * 64 + 32 + j];
            float o = fmaxf((1.f - z) * ng + z * hj, 0.f);
            if (node < NN) Hh[(size_t)node * 32 + j] = (half_t)o;
        }
    }
}

// ---------- K6: GRU layer2 + log_softmax via MFMA + shfl reduce, no LDS ----------
__global__ __launch_bounds__(256) void k6m(const half_t* __restrict__ Xc2,
                                           const half8* __restrict__ W2sw,
                                           const float* __restrict__ bih,
                                           const float* __restrict__ bhh,
                                           float* __restrict__ out) {
    int tid = threadIdx.x;
    int wave = tid >> 6, lane = tid & 63;
    int m16 = lane & 15, q = lane >> 4;
    int nb = blockIdx.x * 64 + wave * 16;
    const half8* xr = (const half8*)(Xc2 + (size_t)(nb + m16) * 96);
    half8 a0 = xr[q], a1 = xr[4 + q], a2 = xr[8 + q];
    f32x4 acc[12];
#pragma unroll
    for (int ct = 0; ct < 12; ++ct) acc[ct] = (f32x4){0.f, 0.f, 0.f, 0.f};
#pragma unroll
    for (int ct = 0; ct < 12; ++ct) {
        acc[ct] = __builtin_amdgcn_mfma_f32_16x16x32_f16(a0, W2sw[ct * 64 + lane], acc[ct], 0, 0, 0);
        acc[ct] = __builtin_amdgcn_mfma_f32_16x16x32_f16(a1, W2sw[(12 + ct) * 64 + lane], acc[ct], 0, 0, 0);
        acc[ct] = __builtin_amdgcn_mfma_f32_16x16x32_f16(a2, W2sw[(24 + ct) * 64 + lane], acc[ct], 0, 0, 0);
    }
    float v[3][4];
#pragma unroll
    for (int ct = 0; ct < 3; ++ct) {
        int j = ct * 16 + m16;
        int jc = (j < NC) ? j : (NC - 1);  // clamp (lanes with j>=40 produce unused values)
        float br = bih[jc] + bhh[jc];
        float bz = bih[NC + jc] + bhh[NC + jc];
        float bi = bih[2 * NC + jc], bh = bhh[2 * NC + jc];
#pragma unroll
        for (int m = 0; m < 4; ++m) {
            int node = nb + q * 4 + m;
            float r = sigm_(acc[ct][m] + br);
            float z = sigm_(acc[3 + ct][m] + bz);
            float ng = tanh_(acc[6 + ct][m] + bi + r * (acc[9 + ct][m] + bh));
            float hj = (float)Xc2[(size_t)node * 96 + 32 + jc];
            v[ct][m] = (1.f - z) * ng + z * hj;
        }
    }
    bool v2ok = (m16 < 8);  // ct=2 covers j=32..39 only for m16<8
#pragma unroll
    for (int m = 0; m < 4; ++m) {
        float mx = fmaxf(v[0][m], v[1][m]);
        if (v2ok) mx = fmaxf(mx, v[2][m]);
#pragma unroll
        for (int d = 1; d < 16; d <<= 1) mx = fmaxf(mx, __shfl_xor(mx, d));
        float se = __expf(v[0][m] - mx) + __expf(v[1][m] - mx) +
                   (v2ok ? __expf(v[2][m] - mx) : 0.f);
#pragma unroll
        for (int d = 1; d < 16; d <<= 1) se += __shfl_xor(se, d);
        float ls = mx + __logf(se);
        int node = nb + q * 4 + m;
        if (node < NN) {
            out[(size_t)node * NC + m16] = v[0][m] - ls;
            out[(size_t)node * NC + 16 + m16] = v[1][m] - ls;
            if (v2ok) out[(size_t)node * NC + 32 + m16] = v[2][m] - ls;
        }
    }
}

extern "C" void kernel_launch(void* const* d_in, const int* in_sizes, int n_in,
                              void* d_out, int out_size, void* d_ws, size_t ws_size,
                              hipStream_t stream) {
    const float* x = (const float*)d_in[0];
    const int* ei = (const int*)d_in[1];
    const float* ew = (const float*)d_in[2];
    const float* W1p = (const float*)d_in[3];
    const float* W1m = (const float*)d_in[4];
    const float* g1wih = (const float*)d_in[5];
    const float* g1whh = (const float*)d_in[6];
    const float* g1bih = (const float*)d_in[7];
    const float* g1bhh = (const float*)d_in[8];
    const float* W2p = (const float*)d_in[9];
    const float* W2m = (const float*)d_in[10];
    const float* g2wih = (const float*)d_in[11];
    const float* g2whh = (const float*)d_in[12];
    const float* g2bih = (const float*)d_in[13];
    const float* g2bhh = (const float*)d_in[14];
    float* ws = (float*)d_ws;

    // workspace layout (float indices), ~43.5 MB total:
    //  Xc   [0, 4801536)       fp16 activations: [NP][64] L1 / [NP][96] L2
    //  Hd   [3201024,4801536)  dense [NN][32] fp16 L1 gather table
    //  Hh   [4801536,6402048)  dense [NN][32] fp16 hrelu table
    //  rec  [0, 4264960)       CSR-build scratch, overlays Xc/Hd (dead before k1)
    //  evs  [6402048,10667008) 196*CAP sorted records
    //  ofs  [10667008,10767008) int[NN] node edge-run start
    //  ocn  [10767008,10867008) int[NN] node edge count
    //  gcur [10867008,10867264)
    //  W1sw/W2sw/M2 tail
    half_t* Xc = (half_t*)ws;
    half_t* Hd = (half_t*)(ws + 3201024);
    half_t* Hh = (half_t*)(ws + 4801536);
    int2* rec = (int2*)ws;
    int2* evs = (int2*)(ws + 6402048);
    int* ofs = (int*)(ws + 10667008);
    int* ocn = (int*)(ws + 10767008);
    int* gcur = (int*)(ws + 10867008);
    half_t* W1sw = (half_t*)(ws + 10867264);
    half_t* W2sw = W1sw + 8192;
    float* M2 = ws + 10880576;
    float* out = (float*)d_out;

    // ---- CSR build (shared by both layers) ----
    k_wpre<<<(NC * 3 * NC + 255) / 256, 256, 0, stream>>>(W2m, g2wih, M2, gcur);
    kA_bucket<<<(NE + EPB - 1) / EPB, 256, 0, stream>>>(ei, ew, gcur, (long long*)rec);
    kB_sort<<<NBK, 256, 0, stream>>>(gcur, rec, evs, ofs, ocn);
    k_wc<<<(8192 + 18432 + 255) / 256, 256, 0, stream>>>(
        W1m, g1wih, W2p, M2, g1whh, g2whh, W1sw, W2sw);

    // ---- layer 1 ----
    k1_proj<<<NN / 8, 256, 0, stream>>>(x, W1p, Xc, Hd);
    k_aggh<64><<<(NN * 4 + 255) / 256, 256, 0, stream>>>(ofs, ocn, evs, Hd, Xc);
    k3m<<<NP / 64, 256, 0, stream>>>(Xc, (const half8*)W1sw, g1bih, g1bhh, Hh);

    // ---- layer 2 ----
    k4_proj2<<<NN / 8, 320, 0, stream>>>(Hh, W2p, Xc);
    k_aggh<96><<<(NN * 4 + 255) / 256, 256, 0, stream>>>(ofs, ocn, evs, Hh, Xc);
    k6m<<<NP / 64, 256, 0, stream>>>(Xc, (const half8*)W2sw, g2bih, g2bhh, out);
}

// Round 5
// 278.350 us; speedup vs baseline: 1.0909x; 1.0909x over previous
//
#include <hip/hip_runtime.h>
#include <math.h>

#define NN 100000
#define NP 100032   // 64 * 1563 (padded node count)
#define NE 2000000
#define FIN 32
#define H 32
#define NC 40

#define NBK 196      // coarse buckets: dst>>9 (512 nodes each)
#define BSH 9
#define CAP 10880    // per-bucket capacity: mean 10240 + ~6.3 sigma
#define EPT 16
#define EPB (256 * EPT)  // 4096 edges per block

#define NPROJ 12500      // prep: proj blocks (8 nodes each)
#define NWB 104          // prep: weight blocks (8192+18432)/256

typedef _Float16 half_t;
typedef __attribute__((ext_vector_type(8))) _Float16 half8;
typedef __attribute__((ext_vector_type(4))) float f32x4;
typedef long long ll2 __attribute__((ext_vector_type(2)));

__device__ __forceinline__ float sigm_(float x) {
    return 1.0f / (1.0f + __expf(-x));
}
__device__ __forceinline__ float tanh_(float x) {
    x = fminf(fmaxf(x, -20.0f), 20.0f);
    float e = __expf(2.0f * x);
    return (e - 1.0f) / (e + 1.0f);
}

// ---------- shared edge-run aggregation body (round-4 proven loop) ----------
// 4 lanes/node, 16B half8 gathers from dense [*][32] fp16 table, NT evs loads.
__device__ __forceinline__ void agg_run(int n, int q,
                                        const int* __restrict__ ofs,
                                        const int* __restrict__ ocn,
                                        const int2* __restrict__ evs,
                                        const half_t* __restrict__ src,
                                        float* acc) {
    const half8* s8 = (const half8*)src + q;       // 16B column chunk; row stride 4 half8
    const long long* ev8 = (const long long*)evs;  // packed (src, w)
    int e = ofs[n];
    int e1 = e + ocn[n];
    if ((e & 1) && e < e1) {  // head: align to 16B for pair loads
        long long r = __builtin_nontemporal_load(ev8 + e);
        float w = __int_as_float((int)(r >> 32));
        half8 hv = s8[(size_t)(r & 0x1FFFF) * 4];
#pragma unroll
        for (int t = 0; t < 8; ++t) acc[t] += w * (float)hv[t];
        ++e;
    }
    for (; e + 8 <= e1; e += 8) {
        ll2 p0 = __builtin_nontemporal_load((const ll2*)(ev8 + e));
        ll2 p1 = __builtin_nontemporal_load((const ll2*)(ev8 + e + 2));
        ll2 p2 = __builtin_nontemporal_load((const ll2*)(ev8 + e + 4));
        ll2 p3 = __builtin_nontemporal_load((const ll2*)(ev8 + e + 6));
        half8 h0 = s8[(size_t)(p0[0] & 0x1FFFF) * 4];
        half8 h1 = s8[(size_t)(p0[1] & 0x1FFFF) * 4];
        half8 h2 = s8[(size_t)(p1[0] & 0x1FFFF) * 4];
        half8 h3 = s8[(size_t)(p1[1] & 0x1FFFF) * 4];
        half8 h4 = s8[(size_t)(p2[0] & 0x1FFFF) * 4];
        half8 h5 = s8[(size_t)(p2[1] & 0x1FFFF) * 4];
        half8 h6 = s8[(size_t)(p3[0] & 0x1FFFF) * 4];
        half8 h7 = s8[(size_t)(p3[1] & 0x1FFFF) * 4];
        float w0 = __int_as_float((int)(p0[0] >> 32));
        float w1 = __int_as_float((int)(p0[1] >> 32));
        float w2 = __int_as_float((int)(p1[0] >> 32));
        float w3 = __int_as_float((int)(p1[1] >> 32));
        float w4 = __int_as_float((int)(p2[0] >> 32));
        float w5 = __int_as_float((int)(p2[1] >> 32));
        float w6 = __int_as_float((int)(p3[0] >> 32));
        float w7 = __int_as_float((int)(p3[1] >> 32));
#pragma unroll
        for (int t = 0; t < 8; ++t) {
            acc[t] += w0 * (float)h0[t];
            acc[t] += w1 * (float)h1[t];
            acc[t] += w2 * (float)h2[t];
            acc[t] += w3 * (float)h3[t];
            acc[t] += w4 * (float)h4[t];
            acc[t] += w5 * (float)h5[t];
            acc[t] += w6 * (float)h6[t];
            acc[t] += w7 * (float)h7[t];
        }
    }
    if (e + 4 <= e1) {
        ll2 p0 = __builtin_nontemporal_load((const ll2*)(ev8 + e));
        ll2 p1 = __builtin_nontemporal_load((const ll2*)(ev8 + e + 2));
        half8 h0 = s8[(size_t)(p0[0] & 0x1FFFF) * 4];
        half8 h1 = s8[(size_t)(p0[1] & 0x1FFFF) * 4];
        half8 h2 = s8[(size_t)(p1[0] & 0x1FFFF) * 4];
        half8 h3 = s8[(size_t)(p1[1] & 0x1FFFF) * 4];
        float w0 = __int_as_float((int)(p0[0] >> 32));
        float w1 = __int_as_float((int)(p0[1] >> 32));
        float w2 = __int_as_float((int)(p1[0] >> 32));
        float w3 = __int_as_float((int)(p1[1] >> 32));
#pragma unroll
        for (int t = 0; t < 8; ++t) {
            acc[t] += w0 * (float)h0[t];
            acc[t] += w1 * (float)h1[t];
            acc[t] += w2 * (float)h2[t];
            acc[t] += w3 * (float)h3[t];
        }
        e += 4;
    }
    if (e + 2 <= e1) {
        ll2 p0 = __builtin_nontemporal_load((const ll2*)(ev8 + e));
        half8 h0 = s8[(size_t)(p0[0] & 0x1FFFF) * 4];
        half8 h1 = s8[(size_t)(p0[1] & 0x1FFFF) * 4];
        float w0 = __int_as_float((int)(p0[0] >> 32));
        float w1 = __int_as_float((int)(p0[1] >> 32));
#pragma unroll
        for (int t = 0; t < 8; ++t) {
            acc[t] += w0 * (float)h0[t];
            acc[t] += w1 * (float)h1[t];
        }
        e += 2;
    }
    if (e < e1) {  // tail single
        long long r = __builtin_nontemporal_load(ev8 + e);
        float w = __int_as_float((int)(r >> 32));
        half8 hv = s8[(size_t)(r & 0x1FFFF) * 4];
#pragma unroll
        for (int t = 0; t < 8; ++t) acc[t] += w * (float)hv[t];
    }
}

// ---------- phase A: coarse-bucket scatter with LDS staging ----------
__global__ __launch_bounds__(256) void kA_bucket(const int* __restrict__ ei,
                                                 const float* __restrict__ ew,
                                                 int* __restrict__ gcur,
                                                 long long* __restrict__ rec) {
    __shared__ long long recs[EPB];   // 32 KB bucket-sorted records
    __shared__ int gdst[EPB];         // 16 KB absolute global slot per record
    __shared__ int cnt[NBK], base[NBK], sofs[NBK];
    __shared__ int ssc[256];
    int tid = threadIdx.x;
    for (int i = tid; i < NBK; i += 256) cnt[i] = 0;
    __syncthreads();
    int e0 = blockIdx.x * EPB;
    int dcache[EPT];
#pragma unroll
    for (int i = 0; i < EPT; ++i) {
        int e = e0 + i * 256 + tid;
        dcache[i] = (e < NE) ? ei[NE + e] : -1;
        if (e < NE) atomicAdd(&cnt[dcache[i] >> BSH], 1);
    }
    __syncthreads();
    int cv = (tid < NBK) ? cnt[tid] : 0;
    ssc[tid] = cv;
    __syncthreads();
    for (int off = 1; off < 256; off <<= 1) {
        int v = (tid >= off) ? ssc[tid - off] : 0;
        __syncthreads();
        ssc[tid] += v;
        __syncthreads();
    }
    if (tid < NBK) {
        sofs[tid] = ssc[tid] - cv;
        base[tid] = atomicAdd(&gcur[tid], cv);  // one global atomic per (block,bucket)
        cnt[tid] = 0;                           // reuse as rank cursor
    }
    __syncthreads();
#pragma unroll
    for (int i = 0; i < EPT; ++i) {
        int e = e0 + i * 256 + tid;
        if (e < NE) {
            int d = dcache[i], s = ei[e];
            int b = d >> BSH;
            int r = atomicAdd(&cnt[b], 1);
            int slot = sofs[b] + r;
            int pos = base[b] + r;
            int lo = s | ((d & 511) << 17);
            recs[slot] = (long long)(unsigned)lo |
                         ((long long)__float_as_int(ew[e]) << 32);
            gdst[slot] = (pos < CAP) ? (b * CAP + pos) : -1;  // overflow guard
        }
    }
    __syncthreads();
    int nrec = min(EPB, NE - e0);
    for (int i = tid; i < nrec; i += 256) {
        int gd = gdst[i];
        if (gd >= 0) rec[gd] = recs[i];
    }
}

// ---------- phase B: per-bucket counting sort by (dst_local, src_slice) ----------
// dst-major slice-minor: node's edges contiguous; slice-ordered within node keeps
// the grid's gathers in ~2 adjacent ~2.1 MB table slices (XCD-L2 resident;
// round-2 proved slice residency cuts FETCH 130->66 MB).
__global__ __launch_bounds__(256) void kB_sort(const int* __restrict__ gcur,
                                               const int2* __restrict__ rec,
                                               int2* __restrict__ evs,
                                               int* __restrict__ ofs,
                                               int* __restrict__ ocn) {
    __shared__ int hist[2048], lofs[2048], ssc[256];
    int tid = threadIdx.x, b = blockIdx.x;
    int nb0 = b << BSH;
    int nnodes = min(512, NN - nb0);
    int cntb = min(gcur[b], CAP);
    for (int i = tid; i < 2048; i += 256) hist[i] = 0;
    __syncthreads();
    const int2* rb = rec + (size_t)b * CAP;
    for (int i = tid; i < cntb; i += 256) {
        int rx = rb[i].x;
        int bin = (((rx >> 17) & 511) << 2) | ((rx & 0x1FFFF) >> 15);
        atomicAdd(&hist[bin], 1);
    }
    __syncthreads();
    int base = tid * 8, ls = 0, lh[8];
#pragma unroll
    for (int j = 0; j < 8; ++j) {
        lh[j] = hist[base + j];
        ls += lh[j];
    }
    ssc[tid] = ls;
    __syncthreads();
    for (int off = 1; off < 256; off <<= 1) {
        int v = (tid >= off) ? ssc[tid - off] : 0;
        __syncthreads();
        ssc[tid] += v;
        __syncthreads();
    }
    int ex = ssc[tid] - ls;
#pragma unroll
    for (int j = 0; j < 8; ++j) {
        lofs[base + j] = ex;
        ex += lh[j];
    }
    __syncthreads();
    for (int l = tid; l < nnodes; l += 256) {
        int c = hist[4 * l] + hist[4 * l + 1] + hist[4 * l + 2] + hist[4 * l + 3];
        ofs[nb0 + l] = b * CAP + lofs[4 * l];
        ocn[nb0 + l] = c;
    }
    __syncthreads();
    for (int i = tid; i < 2048; i += 256) hist[i] = 0;
    __syncthreads();
    int2* eb = evs + (size_t)b * CAP;
    for (int i = tid; i < cntb; i += 256) {
        int2 r = rb[i];
        int bin = (((r.x >> 17) & 511) << 2) | ((r.x & 0x1FFFF) >> 15);
        int rk = atomicAdd(&hist[bin], 1);
        eb[lofs[bin] + rk] = make_int2(r.x & 0x1FFFF, r.y);
    }
}

// ---------- prep: gcur zero + weight tables + x@W1p -> Hd, one dispatch ----------
// Round-18: dispatch-count reduction (10 kernels -> 5; ~10 us/launch gap).
// M2 stage folded away: fold2 = (W2p@W2m)@wih2^T with P2 = W2p@W2m in LDS.
__global__ __launch_bounds__(256) void k_prep(const float* __restrict__ x,
                                              const float* __restrict__ W1p,
                                              const float* __restrict__ W1m,
                                              const float* __restrict__ wih1,
                                              const float* __restrict__ whh1,
                                              const float* __restrict__ W2p,
                                              const float* __restrict__ W2m,
                                              const float* __restrict__ wih2,
                                              const float* __restrict__ whh2,
                                              half_t* __restrict__ Hd,
                                              half_t* __restrict__ W1sw,
                                              half_t* __restrict__ W2sw,
                                              int* __restrict__ gcur) {
    __shared__ float sWp[FIN * H];   // proj weights
    __shared__ float sx[8][FIN];     // proj inputs
    __shared__ float P2l[32 * NC];   // weight blocks: P2 = W2p @ W2m
    int b = blockIdx.x, tid = threadIdx.x;
    if (b < NPROJ) {  // ---- h1 = x @ W1p (8 nodes/block) -> dense Hd ----
        for (int i = tid; i < FIN * H; i += 256) sWp[i] = W1p[i];
        int nb = b * 8;
        int nl = tid >> 5, j = tid & 31;
        int n = nb + nl;
        if (n < NN) sx[nl][j] = x[(size_t)n * FIN + j];
        __syncthreads();
        float acc = 0.f;
#pragma unroll
        for (int k = 0; k < FIN; ++k) acc += sx[nl][k] * sWp[k * H + j];
        if (n < NN) Hd[(size_t)n * 32 + j] = (half_t)acc;
        return;
    }
    int wb = b - NPROJ;
    if (wb == 0 && tid < NBK) gcur[tid] = 0;  // replaces hipMemsetAsync dispatch
    int i = wb * 256 + tid;
    if (i < 8192) {  // ---- layer-1 table (blocks 0..31, uniform branch) ----
        int j = i & 7, lane = (i >> 3) & 63, ct = (i >> 9) & 7, s = i >> 12;
        int k = s * 32 + (lane >> 4) * 8 + j;
        int col = ct * 16 + (lane & 15);
        int g = col >> 5, jj = col & 31;
        float v = 0.f;
        if (g <= 2) {
            if (k < 32) {  // input side (agg): fold W1m @ wih1^T
                float acc = 0.f;
#pragma unroll
                for (int t = 0; t < H; ++t) acc += W1m[k * H + t] * wih1[(g * H + jj) * H + t];
                v = acc;
            } else if (g < 2) {  // r,z hidden side
                v = whh1[(g * H + jj) * H + (k - 32)];
            }                     // g==2 (i_n), k>=32 -> 0
        } else {                  // g==3 (h_n): hidden side only
            if (k >= 32) v = whh1[(2 * H + jj) * H + (k - 32)];
        }
        W1sw[i] = (half_t)v;
    } else {  // ---- layer-2 table (blocks 32..103, uniform branch) ----
        for (int e = tid; e < 32 * NC; e += 256) {  // P2[k][t] = sum_u W2p[k,u]*W2m[u,t]
            int k = e / NC, t = e % NC;
            float a = 0.f;
#pragma unroll
            for (int u = 0; u < NC; ++u) a += W2p[k * NC + u] * W2m[u * NC + t];
            P2l[e] = a;
        }
        __syncthreads();
        int i2 = i - 8192;
        int j = i2 & 7, lane = (i2 >> 3) & 63;
        int tt = i2 >> 9;  // 0..35
        int ct = tt % 12, s = tt / 12;
        int k = s * 32 + (lane >> 4) * 8 + j;  // 0..95
        int col = ct * 16 + (lane & 15);       // 0..191
        int g = col / 48, jj = col % 48;
        float v = 0.f;
        if (jj < NC) {
            if (g <= 2) {
                if (k < 32) {  // input side (agg32): P2 @ wih2^T
                    float acc = 0.f;
#pragma unroll
                    for (int t = 0; t < NC; ++t)
                        acc += P2l[k * NC + t] * wih2[(g * NC + jj) * NC + t];
                    v = acc;
                } else if (k < 72 && g < 2) {  // r,z hidden side
                    v = whh2[(g * NC + jj) * NC + (k - 32)];
                }
            } else {  // g==3 (h_n)
                if (k >= 32 && k < 72) v = whh2[(2 * NC + jj) * NC + (k - 32)];
            }
        }
        W2sw[i2] = (half_t)v;
    }
}

// ---------- L1 fused: agg1(LDS) + MFMA GRU1 + relu -> Hh ----------
__global__ __launch_bounds__(256) void k_l1(const int* __restrict__ ofs,
                                            const int* __restrict__ ocn,
                                            const int2* __restrict__ evs,
                                            const half_t* __restrict__ Hd,
                                            const half8* __restrict__ W1sw,
                                            const float* __restrict__ bih,
                                            const float* __restrict__ bhh,
                                            half_t* __restrict__ Hh) {
    __shared__ half8 aggT[64][4];  // agg result, [node_local][col-quad]
    __shared__ half8 hd8[64][4];   // node-local h1 rows
    int tid = threadIdx.x;
    int nl = tid >> 2, q = tid & 3;
    int n = blockIdx.x * 64 + nl;
    half8 hz;
#pragma unroll
    for (int t = 0; t < 8; ++t) hz[t] = (half_t)0.f;
    hd8[nl][q] = (n < NN) ? ((const half8*)Hd)[(size_t)n * 4 + q] : hz;
    float acc[8] = {0.f, 0.f, 0.f, 0.f, 0.f, 0.f, 0.f, 0.f};
    if (n < NN) agg_run(n, q, ofs, ocn, evs, Hd, acc);
    half8 o;
#pragma unroll
    for (int t = 0; t < 8; ++t) o[t] = (half_t)acc[t];
    aggT[nl][q] = o;
    __syncthreads();
    // MFMA GRU phase (k3m body, A-fragments from LDS)
    int wave = tid >> 6, lane = tid & 63;
    int m16 = lane & 15, qq = lane >> 4;
    int nbw = blockIdx.x * 64 + wave * 16;
    half8 a0 = aggT[wave * 16 + m16][qq];  // k = qq*8.. (agg cols)
    half8 a1 = hd8[wave * 16 + m16][qq];   // k = 32+qq*8.. (h1 cols)
    f32x4 macc[8];
#pragma unroll
    for (int ct = 0; ct < 8; ++ct) macc[ct] = (f32x4){0.f, 0.f, 0.f, 0.f};
#pragma unroll
    for (int ct = 0; ct < 8; ++ct) {
        macc[ct] = __builtin_amdgcn_mfma_f32_16x16x32_f16(a0, W1sw[ct * 64 + lane], macc[ct], 0, 0, 0);
        macc[ct] = __builtin_amdgcn_mfma_f32_16x16x32_f16(a1, W1sw[(8 + ct) * 64 + lane], macc[ct], 0, 0, 0);
    }
#pragma unroll
    for (int ct = 0; ct < 2; ++ct) {
        int j = ct * 16 + m16;
        float br = bih[j] + bhh[j];
        float bz = bih[H + j] + bhh[H + j];
        float bi = bih[2 * H + j], bh = bhh[2 * H + j];
#pragma unroll
        for (int m = 0; m < 4; ++m) {
            int node = nbw + qq * 4 + m;  // C/D: row = quad*4 + reg, col = lane&15
            float r = sigm_(macc[ct][m] + br);
            float z = sigm_(macc[2 + ct][m] + bz);
            float ng = tanh_(macc[4 + ct][m] + bi + r * (macc[6 + ct][m] + bh));
            float hj = (float)hd8[wave * 16 + qq * 4 + m][j >> 3][j & 7];
            float out = fmaxf((1.f - z) * ng + z * hj, 0.f);
            if (node < NN) Hh[(size_t)node * 32 + j] = (half_t)out;
        }
    }
}

// ---------- L2 fused: agg2(LDS) + h2=Hh@W2p(LDS) + MFMA GRU2 + log_softmax ----------
__global__ __launch_bounds__(256) void k_l2(const int* __restrict__ ofs,
                                            const int* __restrict__ ocn,
                                            const int2* __restrict__ evs,
                                            const half_t* __restrict__ Hh,
                                            const half8* __restrict__ W2sw,
                                            const float* __restrict__ W2p,
                                            const float* __restrict__ bih,
                                            const float* __restrict__ bhh,
                                            float* __restrict__ out) {
    __shared__ half8 aggT[64][4];   // agg32 result (X cols 0..31)
    __shared__ half8 hh8[64][4];    // node-local hrelu rows
    __shared__ half8 h2c8[64][8];   // h2 (40 cols) + zero pad to 64 (X cols 32..95)
    __shared__ float sW[FIN * NC];  // W2p
    int tid = threadIdx.x;
    int nl = tid >> 2, q = tid & 3;
    int n = blockIdx.x * 64 + nl;
    for (int i = tid; i < FIN * NC; i += 256) sW[i] = W2p[i];
    half8 hz;
#pragma unroll
    for (int t = 0; t < 8; ++t) hz[t] = (half_t)0.f;
    hh8[nl][q] = (n < NN) ? ((const half8*)Hh)[(size_t)n * 4 + q] : hz;
    float acc[8] = {0.f, 0.f, 0.f, 0.f, 0.f, 0.f, 0.f, 0.f};
    if (n < NN) agg_run(n, q, ofs, ocn, evs, Hh, acc);
    half8 o;
#pragma unroll
    for (int t = 0; t < 8; ++t) o[t] = (half_t)acc[t];
    aggT[nl][q] = o;
    __syncthreads();
    // h2 = hrelu @ W2p: thread (nl,q) computes cols q*10..q*10+9, zeros 40+q*6..
    {
        half8 hr[4];
#pragma unroll
        for (int t = 0; t < 4; ++t) hr[t] = hh8[nl][t];
        half_t* h2row = (half_t*)h2c8[nl];
        float a[10];
#pragma unroll
        for (int j0 = 0; j0 < 10; ++j0) a[j0] = 0.f;
#pragma unroll
        for (int k = 0; k < FIN; ++k) {
            float hk = (float)hr[k >> 3][k & 7];
#pragma unroll
            for (int j0 = 0; j0 < 10; ++j0) a[j0] += hk * sW[k * NC + q * 10 + j0];
        }
#pragma unroll
        for (int j0 = 0; j0 < 10; ++j0) h2row[q * 10 + j0] = (half_t)a[j0];
#pragma unroll
        for (int j0 = 0; j0 < 6; ++j0) h2row[40 + q * 6 + j0] = (half_t)0.f;
    }
    __syncthreads();
    // MFMA GRU + log_softmax phase (k6m body, A-fragments from LDS)
    int wave = tid >> 6, lane = tid & 63;
    int m16 = lane & 15, qq = lane >> 4;
    int nbw = blockIdx.x * 64 + wave * 16;
    half8 a0 = aggT[wave * 16 + m16][qq];      // k = 0..31 (agg)
    half8 a1 = h2c8[wave * 16 + m16][qq];      // k = 32..63 (h2 cols 0..31)
    half8 a2 = h2c8[wave * 16 + m16][4 + qq];  // k = 64..95 (h2 cols 32..39 + pad)
    f32x4 macc[12];
#pragma unroll
    for (int ct = 0; ct < 12; ++ct) macc[ct] = (f32x4){0.f, 0.f, 0.f, 0.f};
#pragma unroll
    for (int ct = 0; ct < 12; ++ct) {
        macc[ct] = __builtin_amdgcn_mfma_f32_16x16x32_f16(a0, W2sw[ct * 64 + lane], macc[ct], 0, 0, 0);
        macc[ct] = __builtin_amdgcn_mfma_f32_16x16x32_f16(a1, W2sw[(12 + ct) * 64 + lane], macc[ct], 0, 0, 0);
        macc[ct] = __builtin_amdgcn_mfma_f32_16x16x32_f16(a2, W2sw[(24 + ct) * 64 + lane], macc[ct], 0, 0, 0);
    }
    float v[3][4];
#pragma unroll
    for (int ct = 0; ct < 3; ++ct) {
        int j = ct * 16 + m16;
        int jc = (j < NC) ? j : (NC - 1);  // clamp (lanes with j>=40 produce unused values)
        float br = bih[jc] + bhh[jc];
        float bz = bih[NC + jc] + bhh[NC + jc];
        float bi = bih[2 * NC + jc], bh = bhh[2 * NC + jc];
#pragma unroll
        for (int m = 0; m < 4; ++m) {
            float r = sigm_(macc[ct][m] + br);
            float z = sigm_(macc[3 + ct][m] + bz);
            float ng = tanh_(macc[6 + ct][m] + bi + r * (macc[9 + ct][m] + bh));
            float hj = (float)((const half_t*)h2c8[wave * 16 + qq * 4 + m])[jc];
            v[ct][m] = (1.f - z) * ng + z * hj;
        }
    }
    bool v2ok = (m16 < 8);  // ct=2 covers j=32..39 only for m16<8
#pragma unroll
    for (int m = 0; m < 4; ++m) {
        float mx = fmaxf(v[0][m], v[1][m]);
        if (v2ok) mx = fmaxf(mx, v[2][m]);
#pragma unroll
        for (int d = 1; d < 16; d <<= 1) mx = fmaxf(mx, __shfl_xor(mx, d));
        float se = __expf(v[0][m] - mx) + __expf(v[1][m] - mx) +
                   (v2ok ? __expf(v[2][m] - mx) : 0.f);
#pragma unroll
        for (int d = 1; d < 16; d <<= 1) se += __shfl_xor(se, d);
        float ls = mx + __logf(se);
        int node = nbw + qq * 4 + m;
        if (node < NN) {
            out[(size_t)node * NC + m16] = v[0][m] - ls;
            out[(size_t)node * NC + 16 + m16] = v[1][m] - ls;
            if (v2ok) out[(size_t)node * NC + 32 + m16] = v[2][m] - ls;
        }
    }
}

extern "C" void kernel_launch(void* const* d_in, const int* in_sizes, int n_in,
                              void* d_out, int out_size, void* d_ws, size_t ws_size,
                              hipStream_t stream) {
    const float* x = (const float*)d_in[0];
    const int* ei = (const int*)d_in[1];
    const float* ew = (const float*)d_in[2];
    const float* W1p = (const float*)d_in[3];
    const float* W1m = (const float*)d_in[4];
    const float* g1wih = (const float*)d_in[5];
    const float* g1whh = (const float*)d_in[6];
    const float* g1bih = (const float*)d_in[7];
    const float* g1bhh = (const float*)d_in[8];
    const float* W2p = (const float*)d_in[9];
    const float* W2m = (const float*)d_in[10];
    const float* g2wih = (const float*)d_in[11];
    const float* g2whh = (const float*)d_in[12];
    const float* g2bih = (const float*)d_in[13];
    const float* g2bhh = (const float*)d_in[14];
    float* ws = (float*)d_ws;

    // workspace layout (float indices), ~47.8 MB (no overlays — rec/Hd now coexist):
    //  rec  [0, 4264960)         kA bucket scratch
    //  evs  [4264960, 8529920)   sorted records
    //  Hd   [8529920, 10130176)  dense [NN][32] fp16 h1 table
    //  Hh   [10130176, 11730432) dense [NN][32] fp16 hrelu table
    //  ofs  [11730432, 11830432) int[NN]
    //  ocn  [11830432, 11930432) int[NN]
    //  gcur [11930432, 11930688)
    //  W1sw/W2sw tail
    long long* rec = (long long*)ws;
    int2* evs = (int2*)(ws + 4264960);
    half_t* Hd = (half_t*)(ws + 8529920);
    half_t* Hh = (half_t*)(ws + 10130176);
    int* ofs = (int*)(ws + 11730432);
    int* ocn = (int*)(ws + 11830432);
    int* gcur = (int*)(ws + 11930432);
    half_t* W1sw = (half_t*)(ws + 11930688);
    half_t* W2sw = W1sw + 8192;
    float* out = (float*)d_out;

    // 5 dispatches total (was 10): launch-gap + intermediate-traffic reduction
    k_prep<<<NPROJ + NWB, 256, 0, stream>>>(x, W1p, W1m, g1wih, g1whh,
                                            W2p, W2m, g2wih, g2whh,
                                            Hd, W1sw, W2sw, gcur);
    kA_bucket<<<(NE + EPB - 1) / EPB, 256, 0, stream>>>(ei, ew, gcur, rec);
    kB_sort<<<NBK, 256, 0, stream>>>(gcur, (const int2*)rec, evs, ofs, ocn);
    k_l1<<<NP / 64, 256, 0, stream>>>(ofs, ocn, evs, Hd, (const half8*)W1sw,
                                      g1bih, g1bhh, Hh);
    k_l2<<<NP / 64, 256, 0, stream>>>(ofs, ocn, evs, Hh, (const half8*)W2sw,
                                      W2p, g2bih, g2bhh, out);
}